// Round 14
// baseline (216.966 us; speedup 1.0000x reference)
//
#include <hip/hip_runtime.h>

#define BB 64
#define SS 1024
#define HH 512
#define EE 512
#define VV 32000
#define PP 40

typedef __attribute__((ext_vector_type(8))) __bf16 bf16x8;
typedef __attribute__((ext_vector_type(4))) float f32x4;
typedef __attribute__((ext_vector_type(8))) unsigned short us8_t;
typedef __attribute__((ext_vector_type(4))) unsigned short us4_t;

__device__ inline float fast_tanh(float x) {
    float e = __expf(-2.0f * fabsf(x));
    float t = (1.0f - e) / (1.0f + e);
    return copysignf(t, x);
}
__device__ inline float sigmf(float x) { return 1.0f / (1.0f + __expf(-x)); }

// non-volatile: pure register computation, schedulable/CSE-able (R12 lesson)
__device__ inline unsigned int cvtpk(float lo, float hi) {
    unsigned int r;
    asm("v_cvt_pk_bf16_f32 %0, %1, %2" : "=v"(r) : "v"(lo), "v"(hi));
    return r;
}
__device__ inline us8_t pack8c(float4 x, float4 y) {
    union { unsigned int u[4]; us8_t v; } r;
    r.u[0] = cvtpk(x.x, x.y); r.u[1] = cvtpk(x.z, x.w);
    r.u[2] = cvtpk(y.x, y.y); r.u[3] = cvtpk(y.z, y.w);
    return r.v;
}

typedef __attribute__((address_space(1))) const unsigned char gas_t;
typedef __attribute__((address_space(3))) unsigned char las_t;
__device__ inline void gload16(const void* g, void* l) {
    __builtin_amdgcn_global_load_lds((gas_t*)g, (las_t*)l, 16, 0, 0);
}

// ---------------------------------------------------------------------------
// k_conv (split from k_prep for attribution): enc f32 -> bf16, 2048 blocks.
// Body identical to R13 conversion branch.
// ---------------------------------------------------------------------------
__global__ __launch_bounds__(256)
void k_conv(const float* __restrict__ enc, unsigned short* __restrict__ enc16) {
    int t = threadIdx.x;
    size_t base = ((size_t)blockIdx.x * 256 + t) * 8;
    float4 xs[8], ys[8];
#pragma unroll
    for (int it = 0; it < 8; ++it) {
        size_t e = base + (size_t)it * 4194304u;   // 524288 threads * 8
        xs[it] = *(const float4*)(enc + e);
        ys[it] = *(const float4*)(enc + e + 4);
    }
#pragma unroll
    for (int it = 0; it < 8; ++it) {
        size_t e = base + (size_t)it * 4194304u;
        *(us8_t*)(enc16 + e) = pack8c(xs[it], ys[it]);
    }
}

// ---------------------------------------------------------------------------
// k_qs (split): qs = hidden @ W_s^T, 64 blocks. Body identical to R13 branch.
// ---------------------------------------------------------------------------
__global__ __launch_bounds__(256)
void k_qs(const float* __restrict__ hidden, const float* __restrict__ Ws,
          float* __restrict__ qs) {
    __shared__ float hb[HH];
    int b = blockIdx.x, t = threadIdx.x;
    for (int i = t; i < HH; i += 256) hb[i] = hidden[b * HH + i];
    __syncthreads();
    for (int n = t; n < HH; n += 256) {
        const float* wr = Ws + (size_t)n * HH;
        float acc = 0.0f;
#pragma unroll 4
        for (int k = 0; k < HH; k += 4) {
            float4 w = *(const float4*)(wr + k);
            acc += w.x * hb[k] + w.y * hb[k + 1] + w.z * hb[k + 2] + w.w * hb[k + 3];
        }
        qs[b * HH + n] = acc;
    }
}

// ---------------------------------------------------------------------------
// k_rest (split): blocks 0..31 W_h f32->bf16; 32..287 gate; 288..295 ctx zero.
// Bodies identical to R13 branches.
// ---------------------------------------------------------------------------
__global__ __launch_bounds__(256)
void k_rest(const float* __restrict__ Wh, const float* __restrict__ pos,
            const float* __restrict__ Wp, const float* __restrict__ bp,
            unsigned short* __restrict__ wh16, float* __restrict__ gate,
            float* __restrict__ ctx) {
    int blk = blockIdx.x, t = threadIdx.x;
    if (blk < 32) {
        int base = blk * 8192 + t * 4;
#pragma unroll
        for (int j = 0; j < 8; ++j) {
            int idx = base + j * 1024;
            float4 x = *(const float4*)(Wh + idx);
            union { unsigned int u[2]; us4_t v; } r;
            r.u[0] = cvtpk(x.x, x.y); r.u[1] = cvtpk(x.z, x.w);
            *(us4_t*)(wh16 + idx) = r.v;
        }
    } else if (blk < 288) {
        int idx = (blk - 32) * 256 + t;  // 0..65535 = b*S+s
        const float* pr = pos + (size_t)idx * PP;
        float acc = bp[0];
#pragma unroll
        for (int j = 0; j < 10; ++j) {
            float4 x = *(const float4*)(pr + j * 4);
            acc += x.x * Wp[j * 4] + x.y * Wp[j * 4 + 1] + x.z * Wp[j * 4 + 2] + x.w * Wp[j * 4 + 3];
        }
        gate[idx] = sigmf(acc);
    } else {
        int idx = (blk - 288) * 256 + t;  // ctx zero
#pragma unroll
        for (int j = 0; j < 16; ++j) ctx[idx * 16 + j] = 0.0f;
    }
}

// ---------------------------------------------------------------------------
// k_scores v9 (T3 minimum 2-phase recipe): C(s,n) = enc16 @ wh16^T.
// Block tile 128s x 128n, BK=64, 8 K-tiles, 4 waves (2m x 2n), wave 64x64.
// BOTH operands staged via global_load_lds width=16. T2 swizzle both-sides
// (rule #21). Per K-tile: STAGE(next) -> ds_read -> MFMA -> vmcnt(0)+barrier.
// grid 2048 = nh(4) x b(64) x sc(8).
// ---------------------------------------------------------------------------
__global__ __launch_bounds__(256)
void k_scores(const unsigned short* __restrict__ enc16,
              const unsigned short* __restrict__ wh16,
              const float* __restrict__ qs, const float* __restrict__ Vw,
              float* __restrict__ part) {
    __shared__ unsigned short As[2][8192];   // 2 x 16KB: [row(128)][k(64)] bf16
    __shared__ unsigned short Bs[2][8192];
    __shared__ float pbuf[2][128];
    int bid = blockIdx.x;
    int nh = bid >> 9, rest = bid & 511;
    int b = rest >> 3, sc = rest & 7;
    int s0 = sc * 128, n0 = nh * 128;
    int tid = threadIdx.x;
    int w = tid >> 6, lane = tid & 63;
    int wm = w >> 1, wn = w & 1;
    int l15 = lane & 15, lq = lane >> 4;

    float qv[4], vw[4];
#pragma unroll
    for (int nf = 0; nf < 4; ++nf) {
        int n = n0 + wn * 64 + nf * 16 + l15;
        qv[nf] = qs[b * HH + n];
        vw[nf] = Vw[n];
    }

    unsigned int colb = (unsigned int)(((lane & 7) * 16) ^ ((lane >> 3) << 4));
    const char* gA0 = (const char*)(enc16 + (size_t)(b * SS + s0) * HH);
    const char* gB0 = (const char*)(wh16 + (size_t)n0 * HH);
    int rbase = w * 32 + (lane >> 3);

    int aswz = (l15 & 7) << 4;
    int aRowB[4], bRowB[4];
#pragma unroll
    for (int mf = 0; mf < 4; ++mf) aRowB[mf] = (wm * 64 + mf * 16 + l15) * 128;
#pragma unroll
    for (int nf = 0; nf < 4; ++nf) bRowB[nf] = (wn * 64 + nf * 16 + l15) * 128;

    f32x4 acc[4][4];
#pragma unroll
    for (int mf = 0; mf < 4; ++mf)
#pragma unroll
        for (int nf = 0; nf < 4; ++nf) acc[mf][nf] = (f32x4){0.f, 0.f, 0.f, 0.f};

#define STAGE(BUF, KT)                                                          \
    {                                                                           \
        _Pragma("unroll")                                                       \
        for (int i = 0; i < 4; ++i) {                                           \
            int row = rbase + i * 8;                                            \
            const char* ga = gA0 + (size_t)row * 1024 + (KT) * 128 + colb;      \
            const char* gb = gB0 + (size_t)row * 1024 + (KT) * 128 + colb;      \
            char* la = (char*)As[BUF] + (w * 32 + i * 8) * 128;                 \
            char* lb = (char*)Bs[BUF] + (w * 32 + i * 8) * 128;                 \
            gload16(ga, la);                                                    \
            gload16(gb, lb);                                                    \
        }                                                                       \
    }

#define COMPUTE(BUF)                                                            \
    {                                                                           \
        _Pragma("unroll")                                                       \
        for (int ks = 0; ks < 2; ++ks) {                                        \
            us8_t af[4], bf[4];                                                 \
            _Pragma("unroll")                                                   \
            for (int mf = 0; mf < 4; ++mf)                                      \
                af[mf] = *(const us8_t*)((const char*)As[BUF] + aRowB[mf] +     \
                                         ((ks * 64 + lq * 16) ^ aswz));         \
            _Pragma("unroll")                                                   \
            for (int nf = 0; nf < 4; ++nf)                                      \
                bf[nf] = *(const us8_t*)((const char*)Bs[BUF] + bRowB[nf] +     \
                                         ((ks * 64 + lq * 16) ^ aswz));         \
            _Pragma("unroll")                                                   \
            for (int mf = 0; mf < 4; ++mf)                                      \
                _Pragma("unroll")                                               \
                for (int nf = 0; nf < 4; ++nf)                                  \
                    acc[mf][nf] = __builtin_amdgcn_mfma_f32_16x16x32_bf16(      \
                        __builtin_bit_cast(bf16x8, af[mf]),                     \
                        __builtin_bit_cast(bf16x8, bf[nf]), acc[mf][nf], 0, 0, 0); \
        }                                                                       \
    }

    STAGE(0, 0);
    asm volatile("s_waitcnt vmcnt(0)" ::: "memory");
    __builtin_amdgcn_s_barrier();

#pragma unroll
    for (int kt2 = 0; kt2 < 4; ++kt2) {
        int kt = kt2 * 2;
        if (kt < 7) STAGE(1, kt + 1);
        COMPUTE(0);
        asm volatile("s_waitcnt vmcnt(0)" ::: "memory");
        __builtin_amdgcn_s_barrier();
        if (kt + 1 < 7) STAGE(0, kt + 2);
        COMPUTE(1);
        asm volatile("s_waitcnt vmcnt(0)" ::: "memory");
        __builtin_amdgcn_s_barrier();
    }
#undef STAGE
#undef COMPUTE

    // epilogue: p(s) = sum_n Vw[n] * tanh(C + qs[n]); reduce n over l15 lanes
#pragma unroll
    for (int mf = 0; mf < 4; ++mf)
#pragma unroll
        for (int r = 0; r < 4; ++r) {
            float p = 0.0f;
#pragma unroll
            for (int nf = 0; nf < 4; ++nf)
                p += vw[nf] * fast_tanh(acc[mf][nf][r] + qv[nf]);
            p += __shfl_xor(p, 1, 64);
            p += __shfl_xor(p, 2, 64);
            p += __shfl_xor(p, 4, 64);
            p += __shfl_xor(p, 8, 64);
            if (l15 == 0) pbuf[wn][wm * 64 + mf * 16 + lq * 4 + r] = p;
        }
    __syncthreads();
    if (tid < 128) {
        part[nh * (BB * SS) + b * SS + s0 + tid] = pbuf[0][tid] + pbuf[1][tid];
    }
}

// ---------------------------------------------------------------------------
// k_context (softmax fused, bf16 enc): combines 4 n-quarter partials,
// redundant row denominator, attn write, context accumulation.
// ---------------------------------------------------------------------------
__global__ __launch_bounds__(256)
void k_context(const unsigned short* __restrict__ enc16, const float* __restrict__ part,
               const float* __restrict__ gate, const unsigned char* __restrict__ mask,
               float* __restrict__ attn, float* __restrict__ ctx) {
    int b = blockIdx.x >> 4, chunk = blockIdx.x & 15;
    int s0 = chunk * 64, t = threadIdx.x;
    int w = t >> 6, ln = t & 63;
    float sum = 0.0f;
#pragma unroll
    for (int j = 0; j < 4; ++j) {
        int s = j * 256 + t;
        float raw = part[b * SS + s] + part[BB * SS + b * SS + s]
                  + part[2 * BB * SS + b * SS + s] + part[3 * BB * SS + b * SS + s];
        float v = mask[b * SS + s] ? -1e30f : raw * gate[b * SS + s];
        sum += __expf(v);
    }
#pragma unroll
    for (int off = 1; off < 64; off <<= 1) sum += __shfl_xor(sum, off, 64);
    __shared__ float sl[4];
    if (ln == 0) sl[w] = sum;
    __syncthreads();
    float inv = 1.0f / (sl[0] + sl[1] + sl[2] + sl[3]);

    __shared__ float aw[64];
    if (t < 64) {
        int s = s0 + t;
        float raw = part[b * SS + s] + part[BB * SS + b * SS + s]
                  + part[2 * BB * SS + b * SS + s] + part[3 * BB * SS + b * SS + s];
        float v = mask[b * SS + s] ? -1e30f : raw * gate[b * SS + s];
        float a = __expf(v) * inv;
        aw[t] = a;
        attn[b * SS + s] = a;
    }
    __syncthreads();

    const unsigned short* eb = enc16 + ((size_t)(b * SS + s0)) * HH + 2 * t;
    float a0 = 0.f, a1 = 0.f;
#pragma unroll 4
    for (int s = 0; s < 64; ++s) {
        unsigned int u = *(const unsigned int*)(eb + (size_t)s * HH);
        a0 += aw[s] * __uint_as_float(u << 16);
        a1 += aw[s] * __uint_as_float(u & 0xffff0000u);
    }
    atomicAdd(&ctx[b * HH + 2 * t], a0);
    atomicAdd(&ctx[b * HH + 2 * t + 1], a1);
}

// ---------------------------------------------------------------------------
// k_build: lstm_in_bf16 = [emb | ctx], h_bf16
// ---------------------------------------------------------------------------
__global__ __launch_bounds__(256)
void k_build(const int* __restrict__ tok, const float* __restrict__ embt,
             const float* __restrict__ ctx, const float* __restrict__ hidden,
             unsigned short* __restrict__ li16, unsigned short* __restrict__ h16v) {
    int b = blockIdx.x, t = threadIdx.x;
    const float* er = embt + (size_t)tok[b] * EE;
    for (int i = 2 * t; i < HH; i += 512) {
        *(unsigned int*)(li16 + b * 1024 + i) = cvtpk(er[i], er[i + 1]);
        *(unsigned int*)(li16 + b * 1024 + 512 + i) = cvtpk(ctx[b * HH + i], ctx[b * HH + i + 1]);
        *(unsigned int*)(h16v + b * HH + i) = cvtpk(hidden[b * HH + i], hidden[b * HH + i + 1]);
    }
}

// ---------------------------------------------------------------------------
// k_gates: gpart[ksl] = lstm_in @ W_ih^T + h @ W_hh^T  (K-slice partials)
// ---------------------------------------------------------------------------
__global__ __launch_bounds__(256)
void k_gates(const unsigned short* __restrict__ li16, const unsigned short* __restrict__ h16v,
             const float* __restrict__ Wih, const float* __restrict__ Whh,
             float* __restrict__ gpart) {
    int nt = blockIdx.x >> 2, ksl = blockIdx.x & 3;
    int wave = threadIdx.x >> 6, lane = threadIdx.x & 63;
    int l15 = lane & 15, lq = lane >> 4, k0 = lq * 8;
    int n0w = nt * 128 + wave * 32;
    f32x4 acc[4][2];
#pragma unroll
    for (int mf = 0; mf < 4; ++mf)
#pragma unroll
        for (int nf = 0; nf < 2; ++nf) acc[mf][nf] = (f32x4){0.f, 0.f, 0.f, 0.f};

    for (int ks = 0; ks < 12; ++ks) {
        int kg = ksl * 384 + ks * 32;
        us8_t af[4];
        if (kg < 1024) {
#pragma unroll
            for (int mf = 0; mf < 4; ++mf)
                af[mf] = *(const us8_t*)(li16 + (mf * 16 + l15) * 1024 + kg + k0);
        } else {
#pragma unroll
            for (int mf = 0; mf < 4; ++mf)
                af[mf] = *(const us8_t*)(h16v + (mf * 16 + l15) * 512 + (kg - 1024) + k0);
        }
#pragma unroll
        for (int nf = 0; nf < 2; ++nf) {
            int n = n0w + nf * 16 + l15;
            us8_t bu;
            if (kg < 1024) {
                const float* wr = Wih + (size_t)n * 1024 + kg + k0;
                bu = pack8c(*(const float4*)wr, *(const float4*)(wr + 4));
            } else {
                const float* wr = Whh + (size_t)n * 512 + (kg - 1024) + k0;
                bu = pack8c(*(const float4*)wr, *(const float4*)(wr + 4));
            }
#pragma unroll
            for (int mf = 0; mf < 4; ++mf)
                acc[mf][nf] = __builtin_amdgcn_mfma_f32_16x16x32_bf16(
                    __builtin_bit_cast(bf16x8, af[mf]),
                    __builtin_bit_cast(bf16x8, bu), acc[mf][nf], 0, 0, 0);
        }
    }
#pragma unroll
    for (int mf = 0; mf < 4; ++mf)
#pragma unroll
        for (int nf = 0; nf < 2; ++nf)
#pragma unroll
            for (int r = 0; r < 4; ++r) {
                int row = mf * 16 + lq * 4 + r;
                int n = n0w + nf * 16 + l15;
                gpart[ksl * (BB * 2048) + row * 2048 + n] = acc[mf][nf][r];
            }
}

// ---------------------------------------------------------------------------
// k_lstm: sum K-slice partials + biases, pointwise cell update
// ---------------------------------------------------------------------------
__global__ __launch_bounds__(512)
void k_lstm(const float* __restrict__ gpart, const float* __restrict__ bih,
            const float* __restrict__ bhh, const float* __restrict__ cell,
            float* __restrict__ oh, float* __restrict__ oc,
            unsigned short* __restrict__ h116) {
    int b = blockIdx.x, t = threadIdx.x;
    float gi = bih[t] + bhh[t];
    float gf = bih[512 + t] + bhh[512 + t];
    float gg = bih[1024 + t] + bhh[1024 + t];
    float go = bih[1536 + t] + bhh[1536 + t];
#pragma unroll
    for (int ksl = 0; ksl < 4; ++ksl) {
        const float* gp = gpart + ksl * (BB * 2048) + b * 2048;
        gi += gp[t];
        gf += gp[512 + t];
        gg += gp[1024 + t];
        go += gp[1536 + t];
    }
    float c0 = cell[b * HH + t];
    float c1 = sigmf(gf) * c0 + sigmf(gi) * fast_tanh(gg);
    float h1 = sigmf(go) * fast_tanh(c1);
    oh[b * HH + t] = h1;
    oc[b * HH + t] = c1;
    h116[b * HH + t] = (unsigned short)(cvtpk(h1, h1) & 0xffffu);
}

// ---------------------------------------------------------------------------
// k_pred: pred = h1 @ W_out^T + b_out  (M=64, N=32000, K=512)
// ---------------------------------------------------------------------------
__global__ __launch_bounds__(512)
void k_pred(const unsigned short* __restrict__ h116, const float* __restrict__ Wout,
            const float* __restrict__ bout, float* __restrict__ pred) {
    int wave = threadIdx.x >> 6, lane = threadIdx.x & 63;
    int l15 = lane & 15, lq = lane >> 4, k0 = lq * 8;
    int n = blockIdx.x * 128 + wave * 16 + l15;
    f32x4 acc[4];
#pragma unroll
    for (int mf = 0; mf < 4; ++mf) acc[mf] = (f32x4){0.f, 0.f, 0.f, 0.f};
    const float* wr = Wout + (size_t)n * HH;
#pragma unroll 4
    for (int ks = 0; ks < 16; ++ks) {
        float4 x = *(const float4*)(wr + ks * 32 + k0);
        float4 y = *(const float4*)(wr + ks * 32 + k0 + 4);
        us8_t bu = pack8c(x, y);
#pragma unroll
        for (int mf = 0; mf < 4; ++mf) {
            us8_t au = *(const us8_t*)(h116 + (mf * 16 + l15) * 512 + ks * 32 + k0);
            acc[mf] = __builtin_amdgcn_mfma_f32_16x16x32_bf16(
                __builtin_bit_cast(bf16x8, au),
                __builtin_bit_cast(bf16x8, bu), acc[mf], 0, 0, 0);
        }
    }
    float bo = bout[n];
#pragma unroll
    for (int mf = 0; mf < 4; ++mf)
#pragma unroll
        for (int r = 0; r < 4; ++r) {
            int row = mf * 16 + lq * 4 + r;
            pred[(size_t)row * VV + n] = acc[mf][r] + bo;
        }
}

// ---------------------------------------------------------------------------
extern "C" void kernel_launch(void* const* d_in, const int* in_sizes, int n_in,
                              void* d_out, int out_size, void* d_ws, size_t ws_size,
                              hipStream_t stream) {
    const int* tok = (const int*)d_in[0];
    const float* hidden = (const float*)d_in[1];
    const float* cell = (const float*)d_in[2];
    const float* enc = (const float*)d_in[3];
    const float* pos = (const float*)d_in[4];
    const unsigned char* mask = (const unsigned char*)d_in[5];
    const float* embt = (const float*)d_in[6];
    const float* Ws = (const float*)d_in[7];
    const float* Wh = (const float*)d_in[8];
    const float* Vw = (const float*)d_in[9];
    const float* Wp = (const float*)d_in[10];
    const float* bp = (const float*)d_in[11];
    const float* Wih = (const float*)d_in[12];
    const float* Whh = (const float*)d_in[13];
    const float* bih = (const float*)d_in[14];
    const float* bhh = (const float*)d_in[15];
    const float* Wout = (const float*)d_in[16];
    const float* bout = (const float*)d_in[17];

    float* out = (float*)d_out;
    float* pred = out;                  // 64*32000
    float* out_h = out + 2048000;       // 64*512
    float* out_c = out + 2080768;       // 64*512
    float* attn = out + 2113536;        // 64*1024

    char* wsb = (char*)d_ws;
    unsigned short* wh16 = (unsigned short*)(wsb);                 // 512KB @0
    float* qs = (float*)(wsb + (512 << 10));                       // 128KB
    float* gate = (float*)(wsb + (640 << 10));                     // 256KB
    float* part = (float*)(wsb + (896 << 10));                     // 1MB (4 slabs)
    float* ctx = (float*)(wsb + (1920 << 10));                     // 128KB
    unsigned short* li16 = (unsigned short*)(wsb + (2048 << 10));  // 128KB
    unsigned short* h16v = (unsigned short*)(wsb + (2176 << 10));  // 64KB
    // enc16 (64MB) lives at 2240K; dead after k_context, so gpart/h116 alias it
    unsigned short* enc16 = (unsigned short*)(wsb + (2240 << 10)); // 64MB [k_conv..k_context]
    float* gpart = (float*)(wsb + (2240 << 10));                   // 2MB  [k_gates..k_lstm]
    unsigned short* h116 = (unsigned short*)(wsb + (4288 << 10));  // 64KB [k_lstm..k_pred]

    hipLaunchKernelGGL(k_conv, dim3(2048), dim3(256), 0, stream, enc, enc16);
    hipLaunchKernelGGL(k_qs, dim3(64), dim3(256), 0, stream, hidden, Ws, qs);
    hipLaunchKernelGGL(k_rest, dim3(296), dim3(256), 0, stream,
                       Wh, pos, Wp, bp, wh16, gate, ctx);
    hipLaunchKernelGGL(k_scores, dim3(2048), dim3(256), 0, stream,
                       enc16, wh16, qs, Vw, part);
    hipLaunchKernelGGL(k_context, dim3(1024), dim3(256), 0, stream,
                       enc16, part, gate, mask, attn, ctx);
    hipLaunchKernelGGL(k_build, dim3(64), dim3(256), 0, stream,
                       tok, embt, ctx, hidden, li16, h16v);
    hipLaunchKernelGGL(k_gates, dim3(64), dim3(256), 0, stream, li16, h16v, Wih, Whh, gpart);
    hipLaunchKernelGGL(k_lstm, dim3(64), dim3(512), 0, stream,
                       gpart, bih, bhh, cell, out_h, out_c, h116);
    hipLaunchKernelGGL(k_pred, dim3(250), dim3(512), 0, stream, h116, Wout, bout, pred);
}

// Round 15
// 171.397 us; speedup vs baseline: 1.2659x; 1.2659x over previous
//
#include <hip/hip_runtime.h>

#define BB 64
#define SS 1024
#define HH 512
#define EE 512
#define VV 32000
#define PP 40

typedef __attribute__((ext_vector_type(8))) __bf16 bf16x8;
typedef __attribute__((ext_vector_type(4))) float f32x4;
typedef __attribute__((ext_vector_type(8))) unsigned short us8_t;
typedef __attribute__((ext_vector_type(4))) unsigned short us4_t;

__device__ inline float fast_tanh(float x) {
    float e = __expf(-2.0f * fabsf(x));
    float t = (1.0f - e) / (1.0f + e);
    return copysignf(t, x);
}
__device__ inline float sigmf(float x) { return 1.0f / (1.0f + __expf(-x)); }

// non-volatile: pure register computation, schedulable/CSE-able (R12 lesson)
__device__ inline unsigned int cvtpk(float lo, float hi) {
    unsigned int r;
    asm("v_cvt_pk_bf16_f32 %0, %1, %2" : "=v"(r) : "v"(lo), "v"(hi));
    return r;
}
__device__ inline us8_t pack8c(float4 x, float4 y) {
    union { unsigned int u[4]; us8_t v; } r;
    r.u[0] = cvtpk(x.x, x.y); r.u[1] = cvtpk(x.z, x.w);
    r.u[2] = cvtpk(y.x, y.y); r.u[3] = cvtpk(y.z, y.w);
    return r.v;
}
__device__ inline us8_t pack8v(f32x4 a, f32x4 b) {
    union { unsigned int u[4]; us8_t v; } r;
    r.u[0] = cvtpk(a[0], a[1]); r.u[1] = cvtpk(a[2], a[3]);
    r.u[2] = cvtpk(b[0], b[1]); r.u[3] = cvtpk(b[2], b[3]);
    return r.v;
}

typedef __attribute__((address_space(1))) const unsigned char gas_t;
typedef __attribute__((address_space(3))) unsigned char las_t;
__device__ inline void gload16(const void* g, void* l) {
    __builtin_amdgcn_global_load_lds((gas_t*)g, (las_t*)l, 16, 0, 0);
}

// ---------------------------------------------------------------------------
// k_pre (concurrent branches): 0..63 qs = hidden @ W_s^T; 64..95 W_h->bf16;
// 96..351 gate = sigmoid(pos_onehot @ W_p + b_p); 352..359 ctx zero.
// (enc conversion ELIMINATED — R14 attribution showed it was ~70us detour.)
// ---------------------------------------------------------------------------
__global__ __launch_bounds__(256)
void k_pre(const float* __restrict__ hidden, const float* __restrict__ Ws,
           const float* __restrict__ Wh, const float* __restrict__ pos,
           const float* __restrict__ Wp, const float* __restrict__ bp,
           unsigned short* __restrict__ wh16, float* __restrict__ qs,
           float* __restrict__ gate, float* __restrict__ ctx) {
    int blk = blockIdx.x, t = threadIdx.x;
    if (blk < 64) {
        __shared__ float hb[HH];
        int b = blk;
        for (int i = t; i < HH; i += 256) hb[i] = hidden[b * HH + i];
        __syncthreads();
        for (int n = t; n < HH; n += 256) {
            const float* wr = Ws + (size_t)n * HH;
            float acc = 0.0f;
#pragma unroll 4
            for (int k = 0; k < HH; k += 4) {
                float4 w = *(const float4*)(wr + k);
                acc += w.x * hb[k] + w.y * hb[k + 1] + w.z * hb[k + 2] + w.w * hb[k + 3];
            }
            qs[b * HH + n] = acc;
        }
    } else if (blk < 96) {
        int base = (blk - 64) * 8192 + t * 4;
#pragma unroll
        for (int j = 0; j < 8; ++j) {
            int idx = base + j * 1024;
            float4 x = *(const float4*)(Wh + idx);
            union { unsigned int u[2]; us4_t v; } r;
            r.u[0] = cvtpk(x.x, x.y); r.u[1] = cvtpk(x.z, x.w);
            *(us4_t*)(wh16 + idx) = r.v;
        }
    } else if (blk < 352) {
        int idx = (blk - 96) * 256 + t;  // 0..65535 = b*S+s
        const float* pr = pos + (size_t)idx * PP;
        float acc = bp[0];
#pragma unroll
        for (int j = 0; j < 10; ++j) {
            float4 x = *(const float4*)(pr + j * 4);
            acc += x.x * Wp[j * 4] + x.y * Wp[j * 4 + 1] + x.z * Wp[j * 4 + 2] + x.w * Wp[j * 4 + 3];
        }
        gate[idx] = sigmf(acc);
    } else {
        int idx = (blk - 352) * 256 + t;  // ctx zero
#pragma unroll
        for (int j = 0; j < 16; ++j) ctx[idx * 16 + j] = 0.0f;
    }
}

// ---------------------------------------------------------------------------
// k_scores v10: C(s,n) = enc(f32) @ wh16^T. No enc16 — A staged as f32 via
// global_load_lds, cvtpk after ds_read. 8 waves (2m x 4n), tile 128s x 256n,
// BK=32, 16 K-tiles. Counted vmcnt(4) (T4): next tile's stage loads stay in
// flight across barriers; drain only at last tile. LDS 64KB -> 2 blocks/CU.
// Swizzle (rule #21): LDS linear dest, pre-swizzled global source, XOR read.
//   A (f32, 128B rows): key (r&7)<<4;  B (bf16, 64B rows): key ((r>>1)&3)<<4.
// grid 1024 = nh(2) x b(64) x sc(8). Epilogue fuses tanh*Vw + n-reduce.
// ---------------------------------------------------------------------------
__global__ __launch_bounds__(512)
void k_scores(const float* __restrict__ enc,
              const unsigned short* __restrict__ wh16,
              const float* __restrict__ qs, const float* __restrict__ Vw,
              float* __restrict__ part) {
    __shared__ float As[2][4096];            // 2 x 16KB: [row(128)][k(32)] f32
    __shared__ unsigned short Bs[2][8192];   // 2 x 16KB: [row(256)][k(32)] bf16
    __shared__ float pbuf[4][128];
    int bid = blockIdx.x;
    int nh = bid >> 9, rest = bid & 511;
    int b = rest >> 3, sc = rest & 7;
    int s0 = sc * 128, n0 = nh * 256;
    int tid = threadIdx.x;
    int w = tid >> 6, lane = tid & 63;
    int wm = w >> 2, wn = w & 3;
    int l15 = lane & 15, lq = lane >> 4;

    float qv[4], vw[4];
#pragma unroll
    for (int nf = 0; nf < 4; ++nf) {
        int n = n0 + wn * 64 + nf * 16 + l15;
        qv[nf] = qs[b * HH + n];
        vw[nf] = Vw[n];
    }

    // staging (per pass, wave-linear LDS dest = w*1024 + lane*16):
    //   A: row = p*64 + w*8 + (lane>>3), src col = ((l&7)*16)^((l>>3)<<4)
    //   B: row = p*128 + w*16 + (lane>>2), src col = ((l&3)*16)^(((l>>3)&3)<<4)
    unsigned int colbA = (unsigned int)(((lane & 7) * 16) ^ ((lane >> 3) << 4));
    unsigned int colbB = (unsigned int)(((lane & 3) * 16) ^ (((lane >> 3) & 3) << 4));
    const char* gA0 = (const char*)(enc + (size_t)(b * SS + s0) * HH);
    const char* gB0 = (const char*)(wh16 + (size_t)n0 * HH);
    int aRowS = w * 8 + (lane >> 3);     // + p*64
    int bRowS = w * 16 + (lane >> 2);    // + p*128
    int ldsOff = w * 1024 + lane * 16;   // + p*8192

    // frag read bases/keys
    int aRowB[4], akey[4], bRowB[4], bkey[4];
#pragma unroll
    for (int mf = 0; mf < 4; ++mf) {
        int r = wm * 64 + mf * 16 + l15;
        aRowB[mf] = r * 128;
        akey[mf] = (r & 7) << 4;
    }
#pragma unroll
    for (int nf = 0; nf < 4; ++nf) {
        int r = wn * 64 + nf * 16 + l15;
        bRowB[nf] = r * 64;
        bkey[nf] = ((r >> 1) & 3) << 4;
    }

    f32x4 acc[4][4];
#pragma unroll
    for (int mf = 0; mf < 4; ++mf)
#pragma unroll
        for (int nf = 0; nf < 4; ++nf) acc[mf][nf] = (f32x4){0.f, 0.f, 0.f, 0.f};

#define STAGE(BUF, KT)                                                          \
    {                                                                           \
        _Pragma("unroll")                                                       \
        for (int p = 0; p < 2; ++p) {                                           \
            const char* ga = gA0 + (size_t)(p * 64 + aRowS) * 2048 +            \
                             (KT) * 128 + colbA;                                \
            gload16(ga, (char*)As[BUF] + p * 8192 + ldsOff);                    \
            const char* gb = gB0 + (size_t)(p * 128 + bRowS) * 1024 +           \
                             (KT) * 64 + colbB;                                 \
            gload16(gb, (char*)Bs[BUF] + p * 8192 + ldsOff);                    \
        }                                                                       \
    }

#define COMPUTE(BUF)                                                            \
    {                                                                           \
        us8_t af[4], bf[4];                                                     \
        _Pragma("unroll")                                                       \
        for (int mf = 0; mf < 4; ++mf) {                                        \
            const char* pa = (const char*)As[BUF] + aRowB[mf];                  \
            f32x4 a0 = *(const f32x4*)(pa + ((lq * 32) ^ akey[mf]));            \
            f32x4 a1 = *(const f32x4*)(pa + ((lq * 32 + 16) ^ akey[mf]));       \
            af[mf] = pack8v(a0, a1);                                            \
        }                                                                       \
        _Pragma("unroll")                                                       \
        for (int nf = 0; nf < 4; ++nf)                                          \
            bf[nf] = *(const us8_t*)((const char*)Bs[BUF] + bRowB[nf] +         \
                                     ((lq * 16) ^ bkey[nf]));                   \
        _Pragma("unroll")                                                       \
        for (int mf = 0; mf < 4; ++mf)                                          \
            _Pragma("unroll")                                                   \
            for (int nf = 0; nf < 4; ++nf)                                      \
                acc[mf][nf] = __builtin_amdgcn_mfma_f32_16x16x32_bf16(          \
                    __builtin_bit_cast(bf16x8, af[mf]),                         \
                    __builtin_bit_cast(bf16x8, bf[nf]), acc[mf][nf], 0, 0, 0);  \
    }

    STAGE(0, 0);
#pragma unroll
    for (int kt = 0; kt < 16; ++kt) {
        if (kt < 15) {
            STAGE((kt + 1) & 1, kt + 1);
            asm volatile("s_waitcnt vmcnt(4)" ::: "memory");
        } else {
            asm volatile("s_waitcnt vmcnt(0)" ::: "memory");
        }
        __builtin_amdgcn_s_barrier();    // buf[kt&1] fully staged (all waves)
        COMPUTE(kt & 1);
        __builtin_amdgcn_s_barrier();    // all reads done before re-stage
    }
#undef STAGE
#undef COMPUTE

    // epilogue: p(s) = sum_n Vw[n]*tanh(C + qs[n]); reduce over nf + l15 lanes
#pragma unroll
    for (int mf = 0; mf < 4; ++mf)
#pragma unroll
        for (int r = 0; r < 4; ++r) {
            float p = 0.0f;
#pragma unroll
            for (int nf = 0; nf < 4; ++nf)
                p += vw[nf] * fast_tanh(acc[mf][nf][r] + qv[nf]);
            p += __shfl_xor(p, 1, 64);
            p += __shfl_xor(p, 2, 64);
            p += __shfl_xor(p, 4, 64);
            p += __shfl_xor(p, 8, 64);
            if (l15 == 0) pbuf[wn][wm * 64 + mf * 16 + lq * 4 + r] = p;
        }
    __syncthreads();
    if (tid < 128) {
        part[nh * (BB * SS) + b * SS + s0 + tid] =
            pbuf[0][tid] + pbuf[1][tid] + pbuf[2][tid] + pbuf[3][tid];
    }
}

// ---------------------------------------------------------------------------
// k_context (softmax fused, f32 enc): combines 2 n-half partials, redundant
// row denominator, attn write, context accumulation.
// grid 1024 = b(64) x chunk(16); thread owns h-pair (2t, 2t+1).
// ---------------------------------------------------------------------------
__global__ __launch_bounds__(256)
void k_context(const float* __restrict__ enc, const float* __restrict__ part,
               const float* __restrict__ gate, const unsigned char* __restrict__ mask,
               float* __restrict__ attn, float* __restrict__ ctx) {
    int b = blockIdx.x >> 4, chunk = blockIdx.x & 15;
    int s0 = chunk * 64, t = threadIdx.x;
    int w = t >> 6, ln = t & 63;
    float sum = 0.0f;
#pragma unroll
    for (int j = 0; j < 4; ++j) {
        int s = j * 256 + t;
        float raw = part[b * SS + s] + part[BB * SS + b * SS + s];
        float v = mask[b * SS + s] ? -1e30f : raw * gate[b * SS + s];
        sum += __expf(v);
    }
#pragma unroll
    for (int off = 1; off < 64; off <<= 1) sum += __shfl_xor(sum, off, 64);
    __shared__ float sl[4];
    if (ln == 0) sl[w] = sum;
    __syncthreads();
    float inv = 1.0f / (sl[0] + sl[1] + sl[2] + sl[3]);

    __shared__ float aw[64];
    if (t < 64) {
        int s = s0 + t;
        float raw = part[b * SS + s] + part[BB * SS + b * SS + s];
        float v = mask[b * SS + s] ? -1e30f : raw * gate[b * SS + s];
        float a = __expf(v) * inv;
        aw[t] = a;
        attn[b * SS + s] = a;
    }
    __syncthreads();

    const float* eb = enc + ((size_t)(b * SS + s0)) * HH + 2 * t;
    float a0 = 0.f, a1 = 0.f;
#pragma unroll 4
    for (int s = 0; s < 64; ++s) {
        float2 u = *(const float2*)(eb + (size_t)s * HH);
        a0 += aw[s] * u.x;
        a1 += aw[s] * u.y;
    }
    atomicAdd(&ctx[b * HH + 2 * t], a0);
    atomicAdd(&ctx[b * HH + 2 * t + 1], a1);
}

// ---------------------------------------------------------------------------
// k_build: lstm_in_bf16 = [emb | ctx], h_bf16
// ---------------------------------------------------------------------------
__global__ __launch_bounds__(256)
void k_build(const int* __restrict__ tok, const float* __restrict__ embt,
             const float* __restrict__ ctx, const float* __restrict__ hidden,
             unsigned short* __restrict__ li16, unsigned short* __restrict__ h16v) {
    int b = blockIdx.x, t = threadIdx.x;
    const float* er = embt + (size_t)tok[b] * EE;
    for (int i = 2 * t; i < HH; i += 512) {
        *(unsigned int*)(li16 + b * 1024 + i) = cvtpk(er[i], er[i + 1]);
        *(unsigned int*)(li16 + b * 1024 + 512 + i) = cvtpk(ctx[b * HH + i], ctx[b * HH + i + 1]);
        *(unsigned int*)(h16v + b * HH + i) = cvtpk(hidden[b * HH + i], hidden[b * HH + i + 1]);
    }
}

// ---------------------------------------------------------------------------
// k_gates: gpart[ksl] = lstm_in @ W_ih^T + h @ W_hh^T  (K-slice partials)
// grid 64 = 16 n-tiles(128) x 4 k-slices(384).
// ---------------------------------------------------------------------------
__global__ __launch_bounds__(256)
void k_gates(const unsigned short* __restrict__ li16, const unsigned short* __restrict__ h16v,
             const float* __restrict__ Wih, const float* __restrict__ Whh,
             float* __restrict__ gpart) {
    int nt = blockIdx.x >> 2, ksl = blockIdx.x & 3;
    int wave = threadIdx.x >> 6, lane = threadIdx.x & 63;
    int l15 = lane & 15, lq = lane >> 4, k0 = lq * 8;
    int n0w = nt * 128 + wave * 32;
    f32x4 acc[4][2];
#pragma unroll
    for (int mf = 0; mf < 4; ++mf)
#pragma unroll
        for (int nf = 0; nf < 2; ++nf) acc[mf][nf] = (f32x4){0.f, 0.f, 0.f, 0.f};

    for (int ks = 0; ks < 12; ++ks) {
        int kg = ksl * 384 + ks * 32;
        us8_t af[4];
        if (kg < 1024) {
#pragma unroll
            for (int mf = 0; mf < 4; ++mf)
                af[mf] = *(const us8_t*)(li16 + (mf * 16 + l15) * 1024 + kg + k0);
        } else {
#pragma unroll
            for (int mf = 0; mf < 4; ++mf)
                af[mf] = *(const us8_t*)(h16v + (mf * 16 + l15) * 512 + (kg - 1024) + k0);
        }
#pragma unroll
        for (int nf = 0; nf < 2; ++nf) {
            int n = n0w + nf * 16 + l15;
            us8_t bu;
            if (kg < 1024) {
                const float* wr = Wih + (size_t)n * 1024 + kg + k0;
                bu = pack8c(*(const float4*)wr, *(const float4*)(wr + 4));
            } else {
                const float* wr = Whh + (size_t)n * 512 + (kg - 1024) + k0;
                bu = pack8c(*(const float4*)wr, *(const float4*)(wr + 4));
            }
#pragma unroll
            for (int mf = 0; mf < 4; ++mf)
                acc[mf][nf] = __builtin_amdgcn_mfma_f32_16x16x32_bf16(
                    __builtin_bit_cast(bf16x8, af[mf]),
                    __builtin_bit_cast(bf16x8, bu), acc[mf][nf], 0, 0, 0);
        }
    }
#pragma unroll
    for (int mf = 0; mf < 4; ++mf)
#pragma unroll
        for (int nf = 0; nf < 2; ++nf)
#pragma unroll
            for (int r = 0; r < 4; ++r) {
                int row = mf * 16 + lq * 4 + r;
                int n = n0w + nf * 16 + l15;
                gpart[ksl * (BB * 2048) + row * 2048 + n] = acc[mf][nf][r];
            }
}

// ---------------------------------------------------------------------------
// k_lstm: sum K-slice partials + biases, pointwise cell update
// ---------------------------------------------------------------------------
__global__ __launch_bounds__(512)
void k_lstm(const float* __restrict__ gpart, const float* __restrict__ bih,
            const float* __restrict__ bhh, const float* __restrict__ cell,
            float* __restrict__ oh, float* __restrict__ oc,
            unsigned short* __restrict__ h116) {
    int b = blockIdx.x, t = threadIdx.x;
    float gi = bih[t] + bhh[t];
    float gf = bih[512 + t] + bhh[512 + t];
    float gg = bih[1024 + t] + bhh[1024 + t];
    float go = bih[1536 + t] + bhh[1536 + t];
#pragma unroll
    for (int ksl = 0; ksl < 4; ++ksl) {
        const float* gp = gpart + ksl * (BB * 2048) + b * 2048;
        gi += gp[t];
        gf += gp[512 + t];
        gg += gp[1024 + t];
        go += gp[1536 + t];
    }
    float c0 = cell[b * HH + t];
    float c1 = sigmf(gf) * c0 + sigmf(gi) * fast_tanh(gg);
    float h1 = sigmf(go) * fast_tanh(c1);
    oh[b * HH + t] = h1;
    oc[b * HH + t] = c1;
    h116[b * HH + t] = (unsigned short)(cvtpk(h1, h1) & 0xffffu);
}

// ---------------------------------------------------------------------------
// k_pred: pred = h1 @ W_out^T + b_out  (M=64, N=32000, K=512)
// ---------------------------------------------------------------------------
__global__ __launch_bounds__(512)
void k_pred(const unsigned short* __restrict__ h116, const float* __restrict__ Wout,
            const float* __restrict__ bout, float* __restrict__ pred) {
    int wave = threadIdx.x >> 6, lane = threadIdx.x & 63;
    int l15 = lane & 15, lq = lane >> 4, k0 = lq * 8;
    int n = blockIdx.x * 128 + wave * 16 + l15;
    f32x4 acc[4];
#pragma unroll
    for (int mf = 0; mf < 4; ++mf) acc[mf] = (f32x4){0.f, 0.f, 0.f, 0.f};
    const float* wr = Wout + (size_t)n * HH;
#pragma unroll 4
    for (int ks = 0; ks < 16; ++ks) {
        float4 x = *(const float4*)(wr + ks * 32 + k0);
        float4 y = *(const float4*)(wr + ks * 32 + k0 + 4);
        us8_t bu = pack8c(x, y);
#pragma unroll
        for (int mf = 0; mf < 4; ++mf) {
            us8_t au = *(const us8_t*)(h116 + (mf * 16 + l15) * 512 + ks * 32 + k0);
            acc[mf] = __builtin_amdgcn_mfma_f32_16x16x32_bf16(
                __builtin_bit_cast(bf16x8, au),
                __builtin_bit_cast(bf16x8, bu), acc[mf], 0, 0, 0);
        }
    }
    float bo = bout[n];
#pragma unroll
    for (int mf = 0; mf < 4; ++mf)
#pragma unroll
        for (int r = 0; r < 4; ++r) {
            int row = mf * 16 + lq * 4 + r;
            pred[(size_t)row * VV + n] = acc[mf][r] + bo;
        }
}

// ---------------------------------------------------------------------------
extern "C" void kernel_launch(void* const* d_in, const int* in_sizes, int n_in,
                              void* d_out, int out_size, void* d_ws, size_t ws_size,
                              hipStream_t stream) {
    const int* tok = (const int*)d_in[0];
    const float* hidden = (const float*)d_in[1];
    const float* cell = (const float*)d_in[2];
    const float* enc = (const float*)d_in[3];
    const float* pos = (const float*)d_in[4];
    const unsigned char* mask = (const unsigned char*)d_in[5];
    const float* embt = (const float*)d_in[6];
    const float* Ws = (const float*)d_in[7];
    const float* Wh = (const float*)d_in[8];
    const float* Vw = (const float*)d_in[9];
    const float* Wp = (const float*)d_in[10];
    const float* bp = (const float*)d_in[11];
    const float* Wih = (const float*)d_in[12];
    const float* Whh = (const float*)d_in[13];
    const float* bih = (const float*)d_in[14];
    const float* bhh = (const float*)d_in[15];
    const float* Wout = (const float*)d_in[16];
    const float* bout = (const float*)d_in[17];

    float* out = (float*)d_out;
    float* pred = out;                  // 64*32000
    float* out_h = out + 2048000;       // 64*512
    float* out_c = out + 2080768;       // 64*512
    float* attn = out + 2113536;        // 64*1024

    char* wsb = (char*)d_ws;
    unsigned short* wh16 = (unsigned short*)(wsb);                 // 512KB @0
    float* qs = (float*)(wsb + (512 << 10));                       // 128KB
    float* gate = (float*)(wsb + (640 << 10));                     // 256KB
    float* part = (float*)(wsb + (896 << 10));                     // 512KB (2 slabs)
    float* ctx = (float*)(wsb + (1408 << 10));                     // 128KB
    unsigned short* li16 = (unsigned short*)(wsb + (1536 << 10));  // 128KB
    unsigned short* h16v = (unsigned short*)(wsb + (1664 << 10));  // 64KB
    float* gpart = (float*)(wsb + (1728 << 10));                   // 2MB
    unsigned short* h116 = (unsigned short*)(wsb + (3776 << 10));  // 64KB

    hipLaunchKernelGGL(k_pre, dim3(360), dim3(256), 0, stream,
                       hidden, Ws, Wh, pos, Wp, bp, wh16, qs, gate, ctx);
    hipLaunchKernelGGL(k_scores, dim3(1024), dim3(512), 0, stream,
                       enc, wh16, qs, Vw, part);
    hipLaunchKernelGGL(k_context, dim3(1024), dim3(256), 0, stream,
                       enc, part, gate, mask, attn, ctx);
    hipLaunchKernelGGL(k_build, dim3(64), dim3(256), 0, stream,
                       tok, embt, ctx, hidden, li16, h16v);
    hipLaunchKernelGGL(k_gates, dim3(64), dim3(256), 0, stream, li16, h16v, Wih, Whh, gpart);
    hipLaunchKernelGGL(k_lstm, dim3(64), dim3(512), 0, stream,
                       gpart, bih, bhh, cell, out_h, out_c, h116);
    hipLaunchKernelGGL(k_pred, dim3(250), dim3(512), 0, stream, h116, Wout, bout, pred);
}